// Round 1
// baseline (193.764 us; speedup 1.0000x reference)
//
#include <hip/hip_runtime.h>
#include <math.h>

#define BB 4
#define NN 512
#define FF 64
#define HH 4

// ---------------- ws layout (floats) ----------------
// dinv : [512]                      off 0
// cvec : [512]                      off 512
// T    : [B*H*N]   = 8192          off 1024
// q_t  : [B*H*N*F] = 2097152       off 9216
// kT   : [B*H*F*N] = 2097152       off 2106368
// pT   : [B*H*32*N]= 262144        off 4203520
// sxd  : [B*N*F]   = 131072        off 4465664
// total 4596736 floats ~= 17.6 MiB

__global__ __launch_bounds__(64) void k_dinv(const float* __restrict__ adj,
                                             float* __restrict__ dinv) {
    int i = blockIdx.x;
    int lane = threadIdx.x;
    float acc = 0.f;
#pragma unroll
    for (int k = 0; k < 8; ++k) acc += adj[i * NN + k * 64 + lane];
    for (int o = 32; o > 0; o >>= 1) acc += __shfl_xor(acc, o);
    if (lane == 0) dinv[i] = 1.0f / sqrtf(acc + 1.0f);   // +1: diagonal of A=adj+I
}

__global__ __launch_bounds__(256) void k_csum(const float* __restrict__ adj,
                                              const float* __restrict__ dinv,
                                              float* __restrict__ cvec) {
    int j = blockIdx.x * 256 + threadIdx.x;
    float acc = 0.f;
    for (int i = 0; i < NN; ++i) acc += dinv[i] * adj[i * NN + j];
    acc += dinv[j];                // diagonal term A[j,j]=adj[j,j]+1 -> dinv[j]*1
    cvec[j] = dinv[j] * acc;
}

// q/k projection. Writes q_t[b][h][i][f] and kT[b][h][f][i] (k transposed).
__global__ __launch_bounds__(256) void k_qk(const float* __restrict__ x,
                                            const float* __restrict__ Wq,
                                            const float* __restrict__ bq,
                                            const float* __restrict__ Wk,
                                            const float* __restrict__ bk,
                                            float* __restrict__ q_t,
                                            float* __restrict__ kT) {
    __shared__ float x_lds[16][64];
    int b = blockIdx.x >> 5;
    int i0 = (blockIdx.x & 31) * 16;
    int tid = threadIdx.x;
#pragma unroll
    for (int k = 0; k < 4; ++k) {
        int idx = k * 256 + tid;
        x_lds[idx >> 6][idx & 63] = x[((long)b * NN + i0 + (idx >> 6)) * FF + (idx & 63)];
    }
    __syncthreads();
    int col = tid, h = col >> 6, f = col & 63;
    float qa[16], ka[16];
    float bqv = bq[col], bkv = bk[col];
#pragma unroll
    for (int i = 0; i < 16; ++i) { qa[i] = bqv; ka[i] = bkv; }
    for (int cc = 0; cc < 64; ++cc) {
        float wq = Wq[cc * 256 + col];
        float wk = Wk[cc * 256 + col];
#pragma unroll
        for (int i = 0; i < 16; ++i) {
            float xv = x_lds[i][cc];
            qa[i] = fmaf(xv, wq, qa[i]);
            ka[i] = fmaf(xv, wk, ka[i]);
        }
    }
    long qbase = ((long)(b * HH + h) * NN + i0) * FF + f;
#pragma unroll
    for (int i = 0; i < 16; ++i) q_t[qbase + (long)i * FF] = qa[i];
    long kbase = ((long)(b * HH + h) * FF + f) * NN + i0;   // 16B aligned (i0 % 16 == 0)
#pragma unroll
    for (int k = 0; k < 4; ++k) {
        float4 v = make_float4(ka[4 * k], ka[4 * k + 1], ka[4 * k + 2], ka[4 * k + 3]);
        *(float4*)(kT + kbase + 4 * k) = v;
    }
}

// Fused: scores (QK^T/sqrt(F)) -> softmax over j -> weighted by noradj[i,j]
// -> partial column sums pT[b][h][itile][j] over the block's 16 i-rows.
__global__ __launch_bounds__(256) void k_scores(const float* __restrict__ q_t,
                                                const float* __restrict__ kT,
                                                const float* __restrict__ adj,
                                                const float* __restrict__ dinv,
                                                float* __restrict__ pT) {
    __shared__ float q_lds[16][64];
    __shared__ float red[16][4];
    __shared__ float red2[16][4];
    int itile = blockIdx.x & 31;
    int h = (blockIdx.x >> 5) & 3;
    int b = blockIdx.x >> 7;
    int i0 = itile * 16;
    int tid = threadIdx.x;
    int bh = b * HH + h;
#pragma unroll
    for (int k = 0; k < 4; ++k) {
        int idx = k * 256 + tid;
        q_lds[idx >> 6][idx & 63] = q_t[((long)bh * NN + i0 + (idx >> 6)) * FF + (idx & 63)];
    }
    __syncthreads();
    int j0 = tid, j1 = tid + 256;
    const float* kb = kT + (long)bh * FF * NN;
    float s0[16], s1[16];
#pragma unroll
    for (int r = 0; r < 16; ++r) { s0[r] = 0.f; s1[r] = 0.f; }
    for (int f4 = 0; f4 < 64; f4 += 4) {
        float kv0[4], kv1[4];
#pragma unroll
        for (int u = 0; u < 4; ++u) {
            kv0[u] = kb[(f4 + u) * NN + j0];
            kv1[u] = kb[(f4 + u) * NN + j1];
        }
#pragma unroll
        for (int r = 0; r < 16; ++r) {
            float4 qv = *(const float4*)&q_lds[r][f4];
            s0[r] = fmaf(qv.x, kv0[0], s0[r]);
            s0[r] = fmaf(qv.y, kv0[1], s0[r]);
            s0[r] = fmaf(qv.z, kv0[2], s0[r]);
            s0[r] = fmaf(qv.w, kv0[3], s0[r]);
            s1[r] = fmaf(qv.x, kv1[0], s1[r]);
            s1[r] = fmaf(qv.y, kv1[1], s1[r]);
            s1[r] = fmaf(qv.z, kv1[2], s1[r]);
            s1[r] = fmaf(qv.w, kv1[3], s1[r]);
        }
    }
    const float scale = 0.125f;   // 1/sqrt(64)
    int wave = tid >> 6, lane = tid & 63;
    float m[16];
#pragma unroll
    for (int r = 0; r < 16; ++r) {
        float v = fmaxf(s0[r], s1[r]);
        for (int o = 32; o > 0; o >>= 1) v = fmaxf(v, __shfl_xor(v, o));
        if (lane == 0) red[r][wave] = v;
    }
    __syncthreads();
#pragma unroll
    for (int r = 0; r < 16; ++r)
        m[r] = fmaxf(fmaxf(red[r][0], red[r][1]), fmaxf(red[r][2], red[r][3]));
    // exp in place; block row-sum
#pragma unroll
    for (int r = 0; r < 16; ++r) {
        s0[r] = expf((s0[r] - m[r]) * scale);
        s1[r] = expf((s1[r] - m[r]) * scale);
        float v = s0[r] + s1[r];
        for (int o = 32; o > 0; o >>= 1) v += __shfl_xor(v, o);
        if (lane == 0) red2[r][wave] = v;
    }
    __syncthreads();
    float dj0 = dinv[j0], dj1 = dinv[j1];
    float pw0 = 0.f, pw1 = 0.f;
#pragma unroll
    for (int r = 0; r < 16; ++r) {
        float Zi = 1.0f / (red2[r][0] + red2[r][1] + red2[r][2] + red2[r][3]);
        int gi = i0 + r;
        float di = dinv[gi];
        float a0 = adj[(long)gi * NN + j0] + (gi == j0 ? 1.f : 0.f);
        float a1 = adj[(long)gi * NN + j1] + (gi == j1 ? 1.f : 0.f);
        pw0 += di * a0 * s0[r] * Zi;
        pw1 += di * a1 * s1[r] * Zi;
    }
    float* o = pT + ((long)bh * 32 + itile) * NN;
    o[j0] = pw0 * dj0;
    o[j1] = pw1 * dj1;
}

__global__ __launch_bounds__(256) void k_treduce(const float* __restrict__ pT,
                                                 float* __restrict__ T) {
    int bh = blockIdx.x >> 1;
    int j = (blockIdx.x & 1) * 256 + threadIdx.x;
    const float* p = pT + (long)bh * 32 * NN + j;
    float acc = 0.f;
#pragma unroll
    for (int it = 0; it < 32; ++it) acc += p[it * NN];
    T[bh * NN + j] = acc;
}

// sxd[b,j,f] = x[b,j,f] * S[b,j,f] * dinv[j]
// S = blin[f]*c[j] + sum_h T[b,h,j]*Wlin[h,f]
__global__ __launch_bounds__(256) void k_sxd(const float* __restrict__ x,
                                             const float* __restrict__ T,
                                             const float* __restrict__ Wlin,
                                             const float* __restrict__ blin,
                                             const float* __restrict__ cvec,
                                             const float* __restrict__ dinv,
                                             float* __restrict__ sxd) {
    int t = blockIdx.x * 256 + threadIdx.x;
    int f = t & 63;
    int j = (t >> 6) & (NN - 1);
    int b = t >> 15;
    float S = blin[f] * cvec[j];
#pragma unroll
    for (int h = 0; h < HH; ++h) S += T[(b * HH + h) * NN + j] * Wlin[h * FF + f];
    sxd[t] = x[t] * S * dinv[j];
}

// out[b,i,:] = relu( (dinv[i] * sum_j (adj[i,j]+I) * sxd[b,j,:]) @ Wfc + bfc )
__global__ __launch_bounds__(256) void k_final(const float* __restrict__ sxd,
                                               const float* __restrict__ adj,
                                               const float* __restrict__ dinv,
                                               const float* __restrict__ Wfc,
                                               const float* __restrict__ bfc,
                                               float* __restrict__ out) {
    __shared__ float sx_lds[64][64];
    __shared__ float adj_lds[8][64];
    __shared__ float wfc_lds[64][64];
    __shared__ float o_lds[8][64];
    int b = blockIdx.x >> 6;
    int i0 = (blockIdx.x & 63) * 8;
    int tid = threadIdx.x;
    int f = tid & 63, r = tid >> 6;   // rows r and r+4
#pragma unroll
    for (int k = 0; k < 16; ++k) {
        int idx = k * 256 + tid;
        wfc_lds[idx >> 6][idx & 63] = Wfc[idx];
    }
    float acc0 = 0.f, acc1 = 0.f;
    for (int jt = 0; jt < 8; ++jt) {
        __syncthreads();
#pragma unroll
        for (int k = 0; k < 16; ++k) {
            int idx = k * 256 + tid;
            sx_lds[idx >> 6][idx & 63] =
                sxd[((long)b * NN + jt * 64 + (idx >> 6)) * FF + (idx & 63)];
        }
#pragma unroll
        for (int k = 0; k < 2; ++k) {
            int idx = k * 256 + tid;
            adj_lds[idx >> 6][idx & 63] = adj[(long)(i0 + (idx >> 6)) * NN + jt * 64 + (idx & 63)];
        }
        __syncthreads();
        int gi0 = i0 + r, gi1 = i0 + r + 4;
        for (int jj = 0; jj < 64; ++jj) {
            int gj = jt * 64 + jj;
            float v = sx_lds[jj][f];
            float a0 = adj_lds[r][jj] + (gi0 == gj ? 1.f : 0.f);
            float a1 = adj_lds[r + 4][jj] + (gi1 == gj ? 1.f : 0.f);
            acc0 = fmaf(a0, v, acc0);
            acc1 = fmaf(a1, v, acc1);
        }
    }
    o_lds[r][f] = acc0 * dinv[i0 + r];
    o_lds[r + 4][f] = acc1 * dinv[i0 + r + 4];
    __syncthreads();
    float o0 = bfc[f], o1 = bfc[f];
    for (int cc = 0; cc < 64; ++cc) {
        float w = wfc_lds[cc][f];
        o0 = fmaf(o_lds[r][cc], w, o0);
        o1 = fmaf(o_lds[r + 4][cc], w, o1);
    }
    out[((long)b * NN + i0 + r) * FF + f] = fmaxf(o0, 0.f);
    out[((long)b * NN + i0 + r + 4) * FF + f] = fmaxf(o1, 0.f);
}

extern "C" void kernel_launch(void* const* d_in, const int* in_sizes, int n_in,
                              void* d_out, int out_size, void* d_ws, size_t ws_size,
                              hipStream_t stream) {
    const float* x    = (const float*)d_in[0];
    const float* adj  = (const float*)d_in[1];
    const float* Wq   = (const float*)d_in[2];
    const float* bq   = (const float*)d_in[3];
    const float* Wk   = (const float*)d_in[4];
    const float* bk   = (const float*)d_in[5];
    const float* Wlin = (const float*)d_in[6];
    const float* blin = (const float*)d_in[7];
    const float* Wfc  = (const float*)d_in[8];
    const float* bfc  = (const float*)d_in[9];
    float* out = (float*)d_out;

    float* ws   = (float*)d_ws;
    float* dinv = ws;                 // 512
    float* cvec = ws + 512;           // 512
    float* T    = ws + 1024;          // 8192
    float* q_t  = ws + 9216;          // 2097152
    float* kT   = ws + 2106368;       // 2097152
    float* pT   = ws + 4203520;       // 262144
    float* sxd  = ws + 4465664;       // 131072

    k_dinv<<<dim3(512), dim3(64), 0, stream>>>(adj, dinv);
    k_csum<<<dim3(2), dim3(256), 0, stream>>>(adj, dinv, cvec);
    k_qk<<<dim3(128), dim3(256), 0, stream>>>(x, Wq, bq, Wk, bk, q_t, kT);
    k_scores<<<dim3(512), dim3(256), 0, stream>>>(q_t, kT, adj, dinv, pT);
    k_treduce<<<dim3(32), dim3(256), 0, stream>>>(pT, T);
    k_sxd<<<dim3(512), dim3(256), 0, stream>>>(x, T, Wlin, blin, cvec, dinv, sxd);
    k_final<<<dim3(256), dim3(256), 0, stream>>>(sxd, adj, dinv, Wfc, bfc, out);
}

// Round 2
// 120.652 us; speedup vs baseline: 1.6060x; 1.6060x over previous
//
#include <hip/hip_runtime.h>
#include <math.h>

#define NN 512
#define FF 64
#define HH 4

// ---------------- ws layout (floats) ----------------
// dinv : [512]              off 0
// psum : [32][512] = 16384  off 512
// T    : [B*H*N]   = 8192   off 16896
// q_t  : [B*H*N*F] = 2097152 off 25088
// kT   : [B*H*F*N] = 2097152 off 2122240
// sxd  : [B*N*F]   = 131072  off 4219392
// total 4350464 floats ~= 16.6 MiB

// Row sums of A=adj+I -> dinv[i] = 1/sqrt(sum). Also zeroes T (atomic target).
__global__ __launch_bounds__(64) void k_dinv(const float* __restrict__ adj,
                                             float* __restrict__ dinv,
                                             float* __restrict__ T) {
    int i = blockIdx.x;
    int lane = threadIdx.x;
    float acc = 0.f;
#pragma unroll
    for (int k = 0; k < 8; ++k) acc += adj[i * NN + k * 64 + lane];
    for (int o = 32; o > 0; o >>= 1) acc += __shfl_xor(acc, o);
    if (lane == 0) dinv[i] = 1.0f / sqrtf(acc + 1.0f);
    if (i < 128) T[i * 64 + lane] = 0.f;   // T has 4*4*512 = 8192 = 128*64
}

// psum[ic][j] = sum_{i in chunk ic} dinv[i]*adj[i,j]  (16 rows per chunk)
__global__ __launch_bounds__(256) void k_csum_part(const float* __restrict__ adj,
                                                   const float* __restrict__ dinv,
                                                   float* __restrict__ psum) {
    int ic = blockIdx.x;              // 0..31
    int j0 = threadIdx.x, j1 = threadIdx.x + 256;
    float a0 = 0.f, a1 = 0.f;
#pragma unroll
    for (int ii = 0; ii < 16; ++ii) {
        int i = ic * 16 + ii;
        float di = dinv[i];
        a0 = fmaf(di, adj[i * NN + j0], a0);
        a1 = fmaf(di, adj[i * NN + j1], a1);
    }
    psum[ic * NN + j0] = a0;
    psum[ic * NN + j1] = a1;
}

// q/k projection, 4-row tiles, q XOR k per block.
// q_t[b][h][i][f]; kT[b][h][f][i] (transposed for coalesced score reads).
__global__ __launch_bounds__(256) void k_qk(const float* __restrict__ x,
                                            const float* __restrict__ Wq,
                                            const float* __restrict__ bq,
                                            const float* __restrict__ Wk,
                                            const float* __restrict__ bk,
                                            float* __restrict__ q_t,
                                            float* __restrict__ kT) {
    __shared__ float x_lds[4][64];
    int blk = blockIdx.x;
    int b = blk >> 8, rest = blk & 255, isK = rest >> 7, itile = rest & 127;
    int i0 = itile * 4;
    int tid = threadIdx.x;
    x_lds[tid >> 6][tid & 63] = x[((long)b * NN + i0 + (tid >> 6)) * FF + (tid & 63)];
    __syncthreads();
    const float* W = isK ? Wk : Wq;
    const float* bias = isK ? bk : bq;
    int col = tid, h = col >> 6, f = col & 63;
    float bv = bias[col];
    float a0 = bv, a1 = bv, a2 = bv, a3 = bv;
    for (int cc = 0; cc < 64; ++cc) {
        float w = W[cc * 256 + col];
        a0 = fmaf(x_lds[0][cc], w, a0);
        a1 = fmaf(x_lds[1][cc], w, a1);
        a2 = fmaf(x_lds[2][cc], w, a2);
        a3 = fmaf(x_lds[3][cc], w, a3);
    }
    int bh = b * HH + h;
    if (!isK) {
        long base = ((long)bh * NN + i0) * FF + f;
        q_t[base] = a0; q_t[base + FF] = a1; q_t[base + 2 * FF] = a2; q_t[base + 3 * FF] = a3;
    } else {
        long base = ((long)bh * FF + f) * NN + i0;   // i0 % 4 == 0 -> 16B aligned
        *(float4*)(kT + base) = make_float4(a0, a1, a2, a3);
    }
}

// Scores -> softmax -> noradj weighting -> atomicAdd column partials into T.
// 8 i-rows per block, 1024 blocks.
__global__ __launch_bounds__(256) void k_scores(const float* __restrict__ q_t,
                                                const float* __restrict__ kT,
                                                const float* __restrict__ adj,
                                                const float* __restrict__ dinv,
                                                float* __restrict__ T) {
    __shared__ float q_lds[8][64];
    __shared__ float red[8][4];
    __shared__ float red2[8][4];
    int blk = blockIdx.x;
    int itile = blk & 63, h = (blk >> 6) & 3, b = blk >> 8;
    int bh = b * HH + h;
    int i0 = itile * 8;
    int tid = threadIdx.x;
#pragma unroll
    for (int k = 0; k < 2; ++k) {
        int idx = k * 256 + tid;
        q_lds[idx >> 6][idx & 63] = q_t[((long)bh * NN + i0 + (idx >> 6)) * FF + (idx & 63)];
    }
    __syncthreads();
    int j0 = tid, j1 = tid + 256;
    const float* kb = kT + (long)bh * FF * NN;
    float s0[8], s1[8];
#pragma unroll
    for (int r = 0; r < 8; ++r) { s0[r] = 0.f; s1[r] = 0.f; }
    for (int f4 = 0; f4 < 64; f4 += 4) {
        float kv0[4], kv1[4];
#pragma unroll
        for (int u = 0; u < 4; ++u) {
            kv0[u] = kb[(f4 + u) * NN + j0];
            kv1[u] = kb[(f4 + u) * NN + j1];
        }
#pragma unroll
        for (int r = 0; r < 8; ++r) {
            float4 qv = *(const float4*)&q_lds[r][f4];
            s0[r] = fmaf(qv.x, kv0[0], s0[r]);
            s0[r] = fmaf(qv.y, kv0[1], s0[r]);
            s0[r] = fmaf(qv.z, kv0[2], s0[r]);
            s0[r] = fmaf(qv.w, kv0[3], s0[r]);
            s1[r] = fmaf(qv.x, kv1[0], s1[r]);
            s1[r] = fmaf(qv.y, kv1[1], s1[r]);
            s1[r] = fmaf(qv.z, kv1[2], s1[r]);
            s1[r] = fmaf(qv.w, kv1[3], s1[r]);
        }
    }
    const float scale = 0.125f;   // 1/sqrt(64)
    int wave = tid >> 6, lane = tid & 63;
    float m[8];
#pragma unroll
    for (int r = 0; r < 8; ++r) {
        float v = fmaxf(s0[r], s1[r]);
        for (int o = 32; o > 0; o >>= 1) v = fmaxf(v, __shfl_xor(v, o));
        if (lane == 0) red[r][wave] = v;
    }
    __syncthreads();
#pragma unroll
    for (int r = 0; r < 8; ++r)
        m[r] = fmaxf(fmaxf(red[r][0], red[r][1]), fmaxf(red[r][2], red[r][3]));
#pragma unroll
    for (int r = 0; r < 8; ++r) {
        s0[r] = expf((s0[r] - m[r]) * scale);
        s1[r] = expf((s1[r] - m[r]) * scale);
        float v = s0[r] + s1[r];
        for (int o = 32; o > 0; o >>= 1) v += __shfl_xor(v, o);
        if (lane == 0) red2[r][wave] = v;
    }
    __syncthreads();
    float dj0 = dinv[j0], dj1 = dinv[j1];
    float pw0 = 0.f, pw1 = 0.f;
#pragma unroll
    for (int r = 0; r < 8; ++r) {
        float Zi = 1.0f / (red2[r][0] + red2[r][1] + red2[r][2] + red2[r][3]);
        int gi = i0 + r;
        float di = dinv[gi];
        float a0 = adj[(long)gi * NN + j0] + (gi == j0 ? 1.f : 0.f);
        float a1 = adj[(long)gi * NN + j1] + (gi == j1 ? 1.f : 0.f);
        pw0 += di * a0 * s0[r] * Zi;
        pw1 += di * a1 * s1[r] * Zi;
    }
    atomicAdd(&T[bh * NN + j0], pw0 * dj0);
    atomicAdd(&T[bh * NN + j1], pw1 * dj1);
}

// sxd[b,j,f] = x[b,j,f] * S[b,j,f] * dinv[j]
// S = blin[f]*c[j] + sum_h T[b,h,j]*Wlin[h,f];  c[j] = dinv[j]*(csum[j] + dinv[j])
__global__ __launch_bounds__(256) void k_sxd(const float* __restrict__ x,
                                             const float* __restrict__ T,
                                             const float* __restrict__ Wlin,
                                             const float* __restrict__ blin,
                                             const float* __restrict__ psum,
                                             const float* __restrict__ dinv,
                                             float* __restrict__ sxd) {
    int t = blockIdx.x * 256 + threadIdx.x;
    int f = t & 63;
    int j = (t >> 6) & (NN - 1);
    int b = t >> 15;
    float cs = 0.f;
#pragma unroll
    for (int p = 0; p < 32; ++p) cs += psum[p * NN + j];
    float dj = dinv[j];
    float cj = dj * (cs + dj);
    float S = blin[f] * cj;
#pragma unroll
    for (int h = 0; h < HH; ++h) S += T[(b * HH + h) * NN + j] * Wlin[h * FF + f];
    sxd[t] = x[t] * S * dj;
}

// out[b,i,:] = relu( (dinv[i] * sum_j (adj[i,j]+I)*sxd[b,j,:]) @ Wfc + bfc )
// 512 threads: f = tid&63, r = (tid>>6)&3 (4 rows), jc = tid>>8 (j-half)
__global__ __launch_bounds__(512) void k_final(const float* __restrict__ sxd,
                                               const float* __restrict__ adj,
                                               const float* __restrict__ dinv,
                                               const float* __restrict__ Wfc,
                                               const float* __restrict__ bfc,
                                               float* __restrict__ out) {
    __shared__ float part[2][4][64];
    __shared__ float m_lds[4][64];
    __shared__ float part2[2][4][64];
    int blk = blockIdx.x;
    int b = blk >> 7, itile = blk & 127;
    int i0 = itile * 4;
    int tid = threadIdx.x;
    int f = tid & 63, r = (tid >> 6) & 3, jc = tid >> 8;
    int i = i0 + r;
    const float* sb = sxd + (long)b * NN * FF + f;
    const float* ar = adj + (long)i * NN;
    float acc = 0.f;
    int jbeg = jc * 256;
#pragma unroll 8
    for (int j = jbeg; j < jbeg + 256; ++j) {
        acc = fmaf(ar[j], sb[(long)j * FF], acc);   // ar: broadcast, sb: coalesced
    }
    if ((i >> 8) == jc) acc += sb[(long)i * FF];    // identity term
    part[jc][r][f] = acc;
    __syncthreads();
    if (jc == 0) m_lds[r][f] = (part[0][r][f] + part[1][r][f]) * dinv[i];
    __syncthreads();
    float o = 0.f;
    int c0 = jc * 32;
#pragma unroll
    for (int cc = 0; cc < 32; ++cc) {
        o = fmaf(m_lds[r][c0 + cc], Wfc[(c0 + cc) * FF + f], o);
    }
    part2[jc][r][f] = o;
    __syncthreads();
    if (jc == 0) {
        float oo = part2[0][r][f] + part2[1][r][f] + bfc[f];
        out[((long)b * NN + i) * FF + f] = fmaxf(oo, 0.f);
    }
}

extern "C" void kernel_launch(void* const* d_in, const int* in_sizes, int n_in,
                              void* d_out, int out_size, void* d_ws, size_t ws_size,
                              hipStream_t stream) {
    const float* x    = (const float*)d_in[0];
    const float* adj  = (const float*)d_in[1];
    const float* Wq   = (const float*)d_in[2];
    const float* bq   = (const float*)d_in[3];
    const float* Wk   = (const float*)d_in[4];
    const float* bk   = (const float*)d_in[5];
    const float* Wlin = (const float*)d_in[6];
    const float* blin = (const float*)d_in[7];
    const float* Wfc  = (const float*)d_in[8];
    const float* bfc  = (const float*)d_in[9];
    float* out = (float*)d_out;

    float* ws   = (float*)d_ws;
    float* dinv = ws;                 // 512
    float* psum = ws + 512;           // 16384
    float* T    = ws + 16896;         // 8192
    float* q_t  = ws + 25088;         // 2097152
    float* kT   = ws + 2122240;       // 2097152
    float* sxd  = ws + 4219392;       // 131072

    k_dinv<<<dim3(512), dim3(64), 0, stream>>>(adj, dinv, T);
    k_csum_part<<<dim3(32), dim3(256), 0, stream>>>(adj, dinv, psum);
    k_qk<<<dim3(1024), dim3(256), 0, stream>>>(x, Wq, bq, Wk, bk, q_t, kT);
    k_scores<<<dim3(1024), dim3(256), 0, stream>>>(q_t, kT, adj, dinv, T);
    k_sxd<<<dim3(512), dim3(256), 0, stream>>>(x, T, Wlin, blin, psum, dinv, sxd);
    k_final<<<dim3(512), dim3(512), 0, stream>>>(sxd, adj, dinv, Wfc, bfc, out);
}